// Round 3
// baseline (274.445 us; speedup 1.0000x reference)
//
#include <hip/hip_runtime.h>
#include <cstdint>

// ---------------------------------------------------------------------------
// AriaTextMoELayer R3: optimized weight transpose (XOR-swizzled LDS, 64x128
// tiles), fc2T/dwT transposes overlapped inside the L1 GEMM launch, split-K2
// for the final down-proj GEMM. bf16 MFMA 16x16x32 everywhere.
// ---------------------------------------------------------------------------

#define E_ 8
#define H_ 1024
#define I_ 1024
#define ISH_ 2048
#define NTOK 2048

typedef unsigned short u16;
using bf16x8 = __attribute__((ext_vector_type(8))) __bf16;
using f32x4  = __attribute__((ext_vector_type(4))) float;

__device__ __forceinline__ u16 f2bf(float f) {
  union { float f; unsigned u; } v; v.f = f;
  unsigned r = v.u + 0x7fffu + ((v.u >> 16) & 1u);  // RNE
  return (u16)(r >> 16);
}
__device__ __forceinline__ float bf2f(u16 u) {
  union { unsigned u; float f; } v; v.u = ((unsigned)u) << 16; return v.f;
}
__device__ __forceinline__ unsigned pk2(float lo, float hi) {
  return ((unsigned)f2bf(hi) << 16) | (unsigned)f2bf(lo);
}

typedef __attribute__((address_space(1))) const void glb_v;
typedef __attribute__((address_space(3))) void lds_v;
__device__ __forceinline__ void gl16(const void* g, void* l) {
  __builtin_amdgcn_global_load_lds((glb_v*)g, (lds_v*)l, 16, 0, 0);
}

// ---------------- router core: one wave per token ----------------
__device__ __forceinline__ void router_body(const float* __restrict__ x,
                                            const float* __restrict__ wr,
                                            float* __restrict__ scores,
                                            int* __restrict__ cnt,
                                            int* __restrict__ list, int tk) {
  int lane = threadIdx.x & 63;
  const float* xr = x + (size_t)tk * H_;
  float acc[E_];
#pragma unroll
  for (int e = 0; e < E_; ++e) acc[e] = 0.f;
  int h0 = lane * 16;
#pragma unroll 4
  for (int i = 0; i < 16; ++i) {
    float xv = xr[h0 + i];
    const float* w = wr + (size_t)(h0 + i) * E_;
#pragma unroll
    for (int e = 0; e < E_; ++e) acc[e] = fmaf(xv, w[e], acc[e]);
  }
#pragma unroll
  for (int off = 32; off > 0; off >>= 1) {
#pragma unroll
    for (int e = 0; e < E_; ++e) acc[e] += __shfl_xor(acc[e], off, 64);
  }
  if (lane == 0) {
    int e0 = 0; float m0 = acc[0];
#pragma unroll
    for (int e = 1; e < E_; ++e) if (acc[e] > m0) { m0 = acc[e]; e0 = e; }
    int e1 = -1; float m1 = -1e30f;
#pragma unroll
    for (int e = 0; e < E_; ++e) if (e != e0 && acc[e] > m1) { m1 = acc[e]; e1 = e; }
    float s0 = 1.f / (1.f + __expf(m1 - m0));
    scores[tk * 2 + 0] = s0;
    scores[tk * 2 + 1] = 1.f - s0;
    int p0 = atomicAdd(&cnt[e0], 1); list[e0 * NTOK + p0] = tk * 2;
    int p1 = atomicAdd(&cnt[e1], 1); list[e1 * NTOK + p1] = tk * 2 + 1;
  }
}

// ---------------- 64k x 128n transpose-convert tile -------------------------
// src fp32 [K][N] -> dst bf16 [N][K]. LDS 16 KB, XOR-swizzled (bank-floor on
// both ds_write_b128 and ds_read_b128). Coalesced global on both sides.
__device__ __forceinline__ void wtrans(const float* __restrict__ src,
                                       u16* __restrict__ dst, int K, int N,
                                       int k0, int n0, void* smem) {
  unsigned* lt = (unsigned*)smem;  // [128 n][32 u32 = 64 k]
  int t = threadIdx.x;
  int c = t & 31, kb = t >> 5;  // c: 32 col-groups of 4; kb: 8 k-blocks of 8
  const float* sp = src + (size_t)(k0 + kb * 8) * N + n0 + (c << 2);
  float v[8][4];
#pragma unroll
  for (int j2 = 0; j2 < 8; ++j2) {
    float4 f = *(const float4*)(sp + (size_t)j2 * N);
    v[j2][0] = f.x; v[j2][1] = f.y; v[j2][2] = f.z; v[j2][3] = f.w;
  }
#pragma unroll
  for (int j = 0; j < 4; ++j) {
    int nl = (c << 2) + j;
    uint4 o = make_uint4(pk2(v[0][j], v[1][j]), pk2(v[2][j], v[3][j]),
                         pk2(v[4][j], v[5][j]), pk2(v[6][j], v[7][j]));
    *(uint4*)&lt[nl * 32 + ((kb ^ (c & 7)) << 2)] = o;
  }
  __syncthreads();
#pragma unroll
  for (int it = 0; it < 4; ++it) {
    int lin = it * 256 + t;
    int nl = lin >> 3, kq = lin & 7;
    uint4 o = *(const uint4*)&lt[nl * 32 + ((kq ^ ((nl >> 2) & 7)) << 2)];
    *(uint4*)(dst + (size_t)(n0 + nl) * K + k0 + kq * 8) = o;
  }
}

// ================= FAST PATH =================

// prep: [0,512) router | [512,1024) x->bf16 | [1024,3072) fc1T |
//       [3072,3328) gwT | [3328,3584) uwT
__global__ __launch_bounds__(256) void prep_k(
    const float* __restrict__ x, const float* __restrict__ wr,
    float* __restrict__ scores, int* __restrict__ cnt, int* __restrict__ list,
    u16* __restrict__ xb,
    const float* __restrict__ fc1, const float* __restrict__ gw,
    const float* __restrict__ uw,
    u16* __restrict__ fc1T, u16* __restrict__ gwT, u16* __restrict__ uwT) {
  __shared__ __align__(16) char psm[16384];
  int bid = blockIdx.x, t = threadIdx.x;
  if (bid < 512) {
    router_body(x, wr, scores, cnt, list, bid * 4 + (t >> 6));
    return;
  }
  if (bid < 1024) {
    const float4* srcx = (const float4*)x;
    ushort4* dstx = (ushort4*)xb;
    int base = (bid - 512) * 1024 + t;
#pragma unroll
    for (int it = 0; it < 4; ++it) {
      float4 v = srcx[base + it * 256];
      ushort4 o;
      o.x = f2bf(v.x); o.y = f2bf(v.y); o.z = f2bf(v.z); o.w = f2bf(v.w);
      dstx[base + it * 256] = o;
    }
    return;
  }
  if (bid < 3072) {  // fc1: 8 experts x [1024][2048], 16 ktiles x 16 ntiles
    int b = bid - 1024;
    int e = b >> 8, q = b & 255;
    wtrans(fc1 + ((size_t)e << 21), fc1T + ((size_t)e << 21), 1024, 2048,
           (q & 15) * 64, (q >> 4) * 128, psm);
  } else if (bid < 3328) {  // gw [1024][2048]
    int q = bid - 3072;
    wtrans(gw, gwT, 1024, 2048, (q & 15) * 64, (q >> 4) * 128, psm);
  } else {  // uw [1024][2048]
    int q = bid - 3328;
    wtrans(uw, uwT, 1024, 2048, (q & 15) * 64, (q >> 4) * 128, psm);
  }
}

// L1: even blockIdx -> fused SwiGLU GEMMs (G3 dense then G1 expert);
//     odd blockIdx  -> rider transposes of fc2T (1024) and dwT (256),
//     interleaved so memory-bound riders overlap compute-bound GEMM blocks.
__global__ __launch_bounds__(256, 2) void swiglu_f_k(
    const u16* __restrict__ xb, const int* __restrict__ cnt,
    const int* __restrict__ list, const u16* __restrict__ fc1T,
    const u16* __restrict__ gwT, const u16* __restrict__ uwT,
    u16* __restrict__ act, u16* __restrict__ tmp,
    const float* __restrict__ fc2, const float* __restrict__ dw,
    u16* __restrict__ fc2T, u16* __restrict__ dwT) {
  __shared__ __align__(16) char smem[24576];
  if (blockIdx.x & 1) {  // rider transposes
    int r = blockIdx.x >> 1;
    if (r < 1024) {  // fc2: 8 x [1024][1024], 16 ktiles x 8 ntiles
      int e = r >> 7, q = r & 127;
      wtrans(fc2 + ((size_t)e << 20), fc2T + ((size_t)e << 20), 1024, 1024,
             (q & 15) * 64, (q >> 4) * 128, smem);
    } else {  // dw [2048][1024], 32 ktiles x 8 ntiles
      int q = r - 1024;
      wtrans(dw, dwT, 2048, 1024, (q & 31) * 64, (q >> 5) * 128, smem);
    }
    return;
  }
  u16 (*As)[32]  = (u16(*)[32])smem;
  u16 (*B1s)[32] = (u16(*)[32])(smem + 8192);
  u16 (*B2s)[32] = (u16(*)[32])(smem + 16384);

  int bid = blockIdx.x >> 1;
  int m0, n0, Me, obase = 0, ldo;
  const u16 *B1, *B2;
  const int* rowmap = nullptr;
  u16* Out;
  if (bid < 256) {  // G3: shared experts
    int mb = bid >> 4, nb = bid & 15;
    m0 = mb * 128; n0 = nb * 128; Me = NTOK;
    B1 = gwT + (size_t)n0 * 1024; B2 = uwT + (size_t)n0 * 1024;
    Out = tmp; ldo = ISH_;
  } else {  // G1: expert fc1
    int b2 = bid - 256; int e = b2 >> 7, r = b2 & 127, mb = r >> 3, nb = r & 7;
    Me = cnt[e]; m0 = mb * 128;
    if (m0 >= Me) return;
    n0 = nb * 128;
    rowmap = list + e * NTOK;
    const u16* fe = fc1T + ((size_t)e << 21);
    B1 = fe + (size_t)n0 * 1024;
    B2 = fe + (size_t)(1024 + n0) * 1024;
    int off = 0;
    for (int q = 0; q < e; ++q) off += cnt[q];
    obase = off;
    Out = act; ldo = I_;
  }
  int t = threadIdx.x, wid = t >> 6, lane = t & 63;
  int wm = wid & 1, wn = wid >> 1, lr = lane & 15, lkg = lane >> 4;
  int cq = lane & 3, crw = lane >> 2;

  const u16 *arow[2], *b1row[2], *b2row[2];
#pragma unroll
  for (int i = 0; i < 2; ++i) {
    int c = wid * 2 + i;
    int rl = m0 + c * 16 + crw;
    int rc = rl < Me ? rl : (Me - 1);
    int tok = rowmap ? (rowmap[rc] >> 1) : rc;
    arow[i] = xb + (size_t)tok * 1024 + cq * 8;
    int rb = c * 16 + crw;
    b1row[i] = B1 + (size_t)rb * 1024 + cq * 8;
    b2row[i] = B2 + (size_t)rb * 1024 + cq * 8;
  }

  f32x4 aP[4][4] = {}, aG[4][4] = {};
  for (int k0 = 0; k0 < 1024; k0 += 32) {
#pragma unroll
    for (int i = 0; i < 2; ++i) {
      int c = wid * 2 + i;
      gl16(arow[i] + k0, (u16*)As + c * 512);
      gl16(b1row[i] + k0, (u16*)B1s + c * 512);
      gl16(b2row[i] + k0, (u16*)B2s + c * 512);
    }
    __syncthreads();
    bf16x8 af[4];
#pragma unroll
    for (int f = 0; f < 4; ++f)
      af[f] = *reinterpret_cast<const bf16x8*>(&As[wm * 64 + f * 16 + lr][lkg * 8]);
#pragma unroll
    for (int fn = 0; fn < 4; ++fn) {
      bf16x8 b1 = *reinterpret_cast<const bf16x8*>(&B1s[wn * 64 + fn * 16 + lr][lkg * 8]);
      bf16x8 b2 = *reinterpret_cast<const bf16x8*>(&B2s[wn * 64 + fn * 16 + lr][lkg * 8]);
#pragma unroll
      for (int fm = 0; fm < 4; ++fm) {
        aP[fm][fn] = __builtin_amdgcn_mfma_f32_16x16x32_bf16(af[fm], b1, aP[fm][fn], 0, 0, 0);
        aG[fm][fn] = __builtin_amdgcn_mfma_f32_16x16x32_bf16(af[fm], b2, aG[fm][fn], 0, 0, 0);
      }
    }
    __syncthreads();
  }
#pragma unroll
  for (int fm = 0; fm < 4; ++fm)
#pragma unroll
    for (int fn = 0; fn < 4; ++fn)
#pragma unroll
      for (int j = 0; j < 4; ++j) {
        int row = m0 + wm * 64 + fm * 16 + lkg * 4 + j;
        if (row < Me) {
          float p = aP[fm][fn][j], g = aG[fm][fn][j];
          float s = p / (1.f + __expf(-p)) * g;
          Out[(size_t)(obase + row) * ldo + n0 + wn * 64 + fn * 16 + lr] = f2bf(s);
        }
      }
}

// Plain GEMM. MODE 0: fc2 (stride 1024, BN=128) -> outbuf[slot]*score (bf16).
//             MODE 1: down (stride 2048, BN=64), split-K2, atomicAdd fp32 out;
//                     ks==0 blocks also add the moe combine terms.
template <int MODE>
__global__ __launch_bounds__(256, 2) void gemm_f_k(
    const u16* __restrict__ A, const u16* __restrict__ Bg,
    const int* __restrict__ cnt, const int* __restrict__ list,
    const float* __restrict__ scores, u16* __restrict__ outb,
    const u16* __restrict__ outb_r, float* __restrict__ out) {
  constexpr int BNx = MODE == 0 ? 128 : 64;
  constexpr int FN = BNx / 32;
  constexpr int KK = MODE == 0 ? 1024 : 2048;  // row stride
  constexpr int BCH = BNx / 64;
  __shared__ u16 As[128][32];
  __shared__ u16 Bs[BNx][32];
  int bid = blockIdx.x;
  int e = 0, m0, n0, Me, ks = 0;
  const u16 *Ab, *Bb;
  if (MODE == 0) {
    e = bid >> 7; int r = bid & 127, mb = r >> 3, nb = r & 7;
    Me = cnt[e]; m0 = mb * 128;
    if (m0 >= Me) return;
    n0 = nb * 128;
    int off = 0;
    for (int q = 0; q < e; ++q) off += cnt[q];
    Ab = A + (size_t)off * KK;
    Bb = Bg + ((size_t)e << 20) + (size_t)n0 * KK;
  } else {
    ks = bid >> 8; int r = bid & 255;
    int mb = r >> 4, nb = r & 15;
    m0 = mb * 128; n0 = nb * 64; Me = NTOK;
    Ab = A + ks * 1024;
    Bb = Bg + (size_t)n0 * KK + ks * 1024;
  }
  int t = threadIdx.x, wid = t >> 6, lane = t & 63;
  int wm = wid & 1, wn = wid >> 1, lr = lane & 15, lkg = lane >> 4;
  int cq = lane & 3, crw = lane >> 2;

  const u16* arow[2];
#pragma unroll
  for (int i = 0; i < 2; ++i) {
    int c = wid * 2 + i;
    int rl = m0 + c * 16 + crw;
    int rc = rl < Me ? rl : (Me - 1);
    arow[i] = Ab + (size_t)rc * KK + cq * 8;
  }
  const u16* brow[BCH];
#pragma unroll
  for (int i = 0; i < BCH; ++i) {
    int c = wid * BCH + i;
    brow[i] = Bb + (size_t)(c * 16 + crw) * KK + cq * 8;
  }

  f32x4 acc[4][FN] = {};
  for (int k0 = 0; k0 < 1024; k0 += 32) {
#pragma unroll
    for (int i = 0; i < 2; ++i) gl16(arow[i] + k0, (u16*)As + (wid * 2 + i) * 512);
#pragma unroll
    for (int i = 0; i < BCH; ++i) gl16(brow[i] + k0, (u16*)Bs + (wid * BCH + i) * 512);
    __syncthreads();
    bf16x8 af[4];
#pragma unroll
    for (int f = 0; f < 4; ++f)
      af[f] = *reinterpret_cast<const bf16x8*>(&As[wm * 64 + f * 16 + lr][lkg * 8]);
#pragma unroll
    for (int fn = 0; fn < FN; ++fn) {
      bf16x8 bb = *reinterpret_cast<const bf16x8*>(&Bs[wn * (BNx / 2) + fn * 16 + lr][lkg * 8]);
#pragma unroll
      for (int fm = 0; fm < 4; ++fm)
        acc[fm][fn] = __builtin_amdgcn_mfma_f32_16x16x32_bf16(af[fm], bb, acc[fm][fn], 0, 0, 0);
    }
    __syncthreads();
  }
#pragma unroll
  for (int fm = 0; fm < 4; ++fm)
#pragma unroll
    for (int fn = 0; fn < FN; ++fn)
#pragma unroll
      for (int j = 0; j < 4; ++j) {
        int row = m0 + wm * 64 + fm * 16 + lkg * 4 + j;
        if (row < Me) {
          float v = acc[fm][fn][j];
          int c = n0 + wn * (BNx / 2) + fn * 16 + lr;
          if (MODE == 0) {
            int slot = list[e * NTOK + row];
            outb[(size_t)slot * H_ + c] = f2bf(v * scores[slot]);
          } else {
            if (ks == 0)
              v += bf2f(outb_r[(size_t)(2 * row) * H_ + c]) +
                   bf2f(outb_r[(size_t)(2 * row + 1) * H_ + c]);
            atomicAdd(&out[(size_t)row * H_ + c], v);
          }
        }
      }
}

// ================= FALLBACK PATH (R1, proven) =================
#define BM 128
#define BN 64
#define BK 32
#define PK (BK + 8)

__global__ void router_k(const float* __restrict__ x, const float* __restrict__ wr,
                         float* __restrict__ scores, int* __restrict__ cnt,
                         int* __restrict__ list) {
  int wid = threadIdx.x >> 6;
  int tk = blockIdx.x * 4 + wid;
  if (tk >= NTOK) return;
  router_body(x, wr, scores, cnt, list, tk);
}

__global__ void offs_k(const int* __restrict__ cnt, int* __restrict__ offs) {
  if (threadIdx.x == 0 && blockIdx.x == 0) {
    int s = 0;
    for (int e = 0; e < E_; ++e) { offs[e] = s; s += cnt[e]; }
  }
}

__global__ void cvt_k(const float* __restrict__ x, u16* __restrict__ xb, int n4) {
  int i = blockIdx.x * blockDim.x + threadIdx.x;
  if (i >= n4) return;
  float4 v = reinterpret_cast<const float4*>(x)[i];
  ushort4 o;
  o.x = f2bf(v.x); o.y = f2bf(v.y); o.z = f2bf(v.z); o.w = f2bf(v.w);
  reinterpret_cast<ushort4*>(xb)[i] = o;
}

template <int EXPERT>
__global__ __launch_bounds__(256) void swiglu_gemm_k(
    const u16* __restrict__ A, int lda,
    const int* __restrict__ list, const int* __restrict__ cnt, const int* __restrict__ offs,
    const float* __restrict__ B1g, const float* __restrict__ B2g, int ldb, long long bstride,
    u16* __restrict__ Out, int ldo, int K) {
  __shared__ u16 As[BM][PK];
  __shared__ u16 Bs[2][BN][PK];
  int e = EXPERT ? blockIdx.z : 0;
  int Me = EXPERT ? cnt[e] : NTOK;
  int m0 = blockIdx.y * BM;
  if (m0 >= Me) return;
  int n0 = blockIdx.x * BN;
  const int* rowmap = EXPERT ? (list + e * NTOK) : nullptr;
  const float* B1 = B1g + (EXPERT ? (long long)e * bstride : 0);
  const float* B2 = B2g + (EXPERT ? (long long)e * bstride : 0);
  int t = threadIdx.x, wid = t >> 6, lane = t & 63;
  int wm = wid & 1, wn = wid >> 1, lr = lane & 15, lkg = lane >> 4;
  f32x4 accP[4][2] = {}, accG[4][2] = {};
  for (int k0 = 0; k0 < K; k0 += BK) {
#pragma unroll
    for (int it = 0; it < 2; ++it) {
      int idx = it * 256 + t, r = idx >> 2, q = idx & 3, row = m0 + r;
      uint4 v = make_uint4(0u, 0u, 0u, 0u);
      if (row < Me) {
        int rg = EXPERT ? (rowmap[row] >> 1) : row;
        v = *reinterpret_cast<const uint4*>(A + (size_t)rg * lda + k0 + q * 8);
      }
      *reinterpret_cast<uint4*>(&As[r][q * 8]) = v;
    }
#pragma unroll
    for (int b = 0; b < 2; ++b) {
      const float* Bp = b ? B2 : B1;
#pragma unroll
      for (int it = 0; it < 2; ++it) {
        int idx = (it * 256 + t) * 4, kr = idx >> 6, c = idx & 63;
        float4 f = *reinterpret_cast<const float4*>(Bp + (size_t)(k0 + kr) * ldb + n0 + c);
        Bs[b][c + 0][kr] = f2bf(f.x); Bs[b][c + 1][kr] = f2bf(f.y);
        Bs[b][c + 2][kr] = f2bf(f.z); Bs[b][c + 3][kr] = f2bf(f.w);
      }
    }
    __syncthreads();
    bf16x8 af[4];
#pragma unroll
    for (int fm = 0; fm < 4; ++fm)
      af[fm] = *reinterpret_cast<const bf16x8*>(&As[wm * 64 + fm * 16 + lr][lkg * 8]);
#pragma unroll
    for (int fn = 0; fn < 2; ++fn) {
      bf16x8 bp = *reinterpret_cast<const bf16x8*>(&Bs[0][wn * 32 + fn * 16 + lr][lkg * 8]);
      bf16x8 bg = *reinterpret_cast<const bf16x8*>(&Bs[1][wn * 32 + fn * 16 + lr][lkg * 8]);
#pragma unroll
      for (int fm = 0; fm < 4; ++fm) {
        accP[fm][fn] = __builtin_amdgcn_mfma_f32_16x16x32_bf16(af[fm], bp, accP[fm][fn], 0, 0, 0);
        accG[fm][fn] = __builtin_amdgcn_mfma_f32_16x16x32_bf16(af[fm], bg, accG[fm][fn], 0, 0, 0);
      }
    }
    __syncthreads();
  }
#pragma unroll
  for (int fm = 0; fm < 4; ++fm)
#pragma unroll
    for (int fn = 0; fn < 2; ++fn)
#pragma unroll
      for (int j = 0; j < 4; ++j) {
        int grow = wm * 64 + fm * 16 + lkg * 4 + j, gcol = wn * 32 + fn * 16 + lr;
        int row = m0 + grow;
        if (row < Me) {
          float p = accP[fm][fn][j], g = accG[fm][fn][j];
          float s = p / (1.f + __expf(-p)) * g;
          int orow = EXPERT ? (offs[e] + row) : row;
          Out[(size_t)orow * ldo + n0 + gcol] = f2bf(s);
        }
      }
}

template <int EXPERT>
__global__ __launch_bounds__(256) void out_gemm_k(
    const u16* __restrict__ A, int lda,
    const int* __restrict__ cnt, const int* __restrict__ offs,
    const int* __restrict__ list, const float* __restrict__ scores,
    const float* __restrict__ Bg, int ldb, long long bstride,
    float* __restrict__ Out, const float* __restrict__ outbuf, int K) {
  __shared__ u16 As[BM][PK];
  __shared__ u16 Bs[BN][PK];
  int e = EXPERT ? blockIdx.z : 0;
  int Me = EXPERT ? cnt[e] : NTOK;
  int m0 = blockIdx.y * BM;
  if (m0 >= Me) return;
  int n0 = blockIdx.x * BN;
  const float* B = Bg + (EXPERT ? (long long)e * bstride : 0);
  int aoff = EXPERT ? offs[e] : 0;
  int t = threadIdx.x, wid = t >> 6, lane = t & 63;
  int wm = wid & 1, wn = wid >> 1, lr = lane & 15, lkg = lane >> 4;
  f32x4 acc[4][2] = {};
  for (int k0 = 0; k0 < K; k0 += BK) {
#pragma unroll
    for (int it = 0; it < 2; ++it) {
      int idx = it * 256 + t, r = idx >> 2, q = idx & 3, row = m0 + r;
      uint4 v = make_uint4(0u, 0u, 0u, 0u);
      if (row < Me)
        v = *reinterpret_cast<const uint4*>(A + (size_t)(aoff + row) * lda + k0 + q * 8);
      *reinterpret_cast<uint4*>(&As[r][q * 8]) = v;
    }
#pragma unroll
    for (int it = 0; it < 2; ++it) {
      int idx = (it * 256 + t) * 4, kr = idx >> 6, c = idx & 63;
      float4 f = *reinterpret_cast<const float4*>(B + (size_t)(k0 + kr) * ldb + n0 + c);
      Bs[c + 0][kr] = f2bf(f.x); Bs[c + 1][kr] = f2bf(f.y);
      Bs[c + 2][kr] = f2bf(f.z); Bs[c + 3][kr] = f2bf(f.w);
    }
    __syncthreads();
    bf16x8 af[4];
#pragma unroll
    for (int fm = 0; fm < 4; ++fm)
      af[fm] = *reinterpret_cast<const bf16x8*>(&As[wm * 64 + fm * 16 + lr][lkg * 8]);
#pragma unroll
    for (int fn = 0; fn < 2; ++fn) {
      bf16x8 bb = *reinterpret_cast<const bf16x8*>(&Bs[wn * 32 + fn * 16 + lr][lkg * 8]);
#pragma unroll
      for (int fm = 0; fm < 4; ++fm)
        acc[fm][fn] = __builtin_amdgcn_mfma_f32_16x16x32_bf16(af[fm], bb, acc[fm][fn], 0, 0, 0);
    }
    __syncthreads();
  }
#pragma unroll
  for (int fm = 0; fm < 4; ++fm)
#pragma unroll
    for (int fn = 0; fn < 2; ++fn)
#pragma unroll
      for (int j = 0; j < 4; ++j) {
        int grow = wm * 64 + fm * 16 + lkg * 4 + j, gcol = wn * 32 + fn * 16 + lr;
        int row = m0 + grow;
        if (row < Me) {
          float v = acc[fm][fn][j];
          int c = n0 + gcol;
          if (EXPERT) {
            int slot = list[e * NTOK + row];
            Out[(size_t)slot * H_ + c] = v * scores[slot];
          } else {
            Out[(size_t)row * H_ + c] =
                v + outbuf[(size_t)(2 * row) * H_ + c] + outbuf[(size_t)(2 * row + 1) * H_ + c];
          }
        }
      }
}

// ---------------------------------------------------------------------------
extern "C" void kernel_launch(void* const* d_in, const int* in_sizes, int n_in,
                              void* d_out, int out_size, void* d_ws, size_t ws_size,
                              hipStream_t stream) {
  const float* x   = (const float*)d_in[0];
  const float* wr  = (const float*)d_in[1];
  const float* fc1 = (const float*)d_in[2];
  const float* fc2 = (const float*)d_in[3];
  const float* gw  = (const float*)d_in[4];
  const float* uw  = (const float*)d_in[5];
  const float* dw  = (const float*)d_in[6];
  float* out = (float*)d_out;
  char* ws = (char*)d_ws;

  const size_t NEED_FAST = 131072ull + (88ull << 20);
  if (ws_size >= NEED_FAST) {
    float* scores = (float*)ws;
    int* cnt  = (int*)(ws + 16384);
    int* list = (int*)(ws + 16512);
    u16* xb   = (u16*)(ws + 131072);
    u16* act  = (u16*)(ws + 131072 + (4ll << 20));
    u16* tmp  = (u16*)(ws + 131072 + (12ll << 20));
    u16* outb = (u16*)(ws + 131072 + (20ll << 20));
    u16* fc1T = (u16*)(ws + 131072 + (28ll << 20));
    u16* fc2T = (u16*)(ws + 131072 + (60ll << 20));
    u16* gwT  = (u16*)(ws + 131072 + (76ll << 20));
    u16* uwT  = (u16*)(ws + 131072 + (80ll << 20));
    u16* dwT  = (u16*)(ws + 131072 + (84ll << 20));

    hipMemsetAsync(cnt, 0, 128, stream);
    hipMemsetAsync(out, 0, (size_t)NTOK * H_ * sizeof(float), stream);
    prep_k<<<3584, 256, 0, stream>>>(x, wr, scores, cnt, list, xb,
                                     fc1, gw, uw, fc1T, gwT, uwT);
    swiglu_f_k<<<2560, 256, 0, stream>>>(xb, cnt, list, fc1T, gwT, uwT, act, tmp,
                                         fc2, dw, fc2T, dwT);
    gemm_f_k<0><<<1024, 256, 0, stream>>>(act, fc2T, cnt, list, scores, outb, nullptr, nullptr);
    gemm_f_k<1><<<512, 256, 0, stream>>>(tmp, dwT, nullptr, nullptr, nullptr, nullptr, outb, out);
  } else {
    float* scores = (float*)(ws);
    int*   cnt    = (int*)(ws + (16 << 10));
    int*   offs   = (int*)(ws + (16 << 10) + 128);
    int*   list   = (int*)(ws + (16 << 10) + 256);
    u16*   xb     = (u16*)(ws + (96 << 10));
    u16*   act    = (u16*)(ws + (96 << 10) + (4ll << 20));
    u16*   tmp    = (u16*)(ws + (96 << 10) + (12ll << 20));
    float* outbuf = (float*)(ws + (96 << 10) + (20ll << 20));

    hipMemsetAsync(cnt, 0, E_ * sizeof(int), stream);
    router_k<<<NTOK / 4, 256, 0, stream>>>(x, wr, scores, cnt, list);
    offs_k<<<1, 64, 0, stream>>>(cnt, offs);
    cvt_k<<<(NTOK * H_ / 4 + 255) / 256, 256, 0, stream>>>(x, xb, NTOK * H_ / 4);
    swiglu_gemm_k<1><<<dim3(I_ / BN, NTOK / BM, E_), 256, 0, stream>>>(
        xb, H_, list, cnt, offs, fc1, fc1 + I_, 2 * I_, (long long)H_ * 2 * I_, act, I_, H_);
    out_gemm_k<1><<<dim3(H_ / BN, NTOK / BM, E_), 256, 0, stream>>>(
        act, I_, cnt, offs, list, scores, fc2, H_, (long long)I_ * H_, outbuf, nullptr, I_);
    swiglu_gemm_k<0><<<dim3(ISH_ / BN, NTOK / BM, 1), 256, 0, stream>>>(
        xb, H_, nullptr, nullptr, nullptr, gw, uw, ISH_, 0, tmp, ISH_, H_);
    out_gemm_k<0><<<dim3(H_ / BN, NTOK / BM, 1), 256, 0, stream>>>(
        tmp, ISH_, nullptr, nullptr, nullptr, nullptr, dw, H_, 0, out, outbuf, ISH_);
  }
  (void)in_sizes; (void)n_in; (void)out_size;
}

// Round 4
// 254.414 us; speedup vs baseline: 1.0787x; 1.0787x over previous
//
#include <hip/hip_runtime.h>
#include <cstdint>

// ---------------------------------------------------------------------------
// AriaTextMoELayer R4: prep (router + convert + ALL weight transposes via
// XOR-swizzled LDS) -> dbuf swiglu GEMM (fc1 expert + shared gate/up) ->
// fused fc2/down GEMM with fp32 atomicAdd epilogue into out. bf16 MFMA.
// ---------------------------------------------------------------------------

#define E_ 8
#define H_ 1024
#define I_ 1024
#define ISH_ 2048
#define NTOK 2048

typedef unsigned short u16;
using bf16x8 = __attribute__((ext_vector_type(8))) __bf16;
using f32x4  = __attribute__((ext_vector_type(4))) float;

__device__ __forceinline__ u16 f2bf(float f) {
  union { float f; unsigned u; } v; v.f = f;
  unsigned r = v.u + 0x7fffu + ((v.u >> 16) & 1u);  // RNE
  return (u16)(r >> 16);
}
__device__ __forceinline__ float bf2f(u16 u) {
  union { unsigned u; float f; } v; v.u = ((unsigned)u) << 16; return v.f;
}
__device__ __forceinline__ unsigned pk2(float lo, float hi) {
  return ((unsigned)f2bf(hi) << 16) | (unsigned)f2bf(lo);
}

typedef __attribute__((address_space(1))) const void glb_v;
typedef __attribute__((address_space(3))) void lds_v;
__device__ __forceinline__ void gl16(const void* g, void* l) {
  __builtin_amdgcn_global_load_lds((glb_v*)g, (lds_v*)l, 16, 0, 0);
}

// ---------------- router core: one wave per token ----------------
__device__ __forceinline__ void router_body(const float* __restrict__ x,
                                            const float* __restrict__ wr,
                                            float* __restrict__ scores,
                                            int* __restrict__ cnt,
                                            int* __restrict__ list, int tk) {
  int lane = threadIdx.x & 63;
  const float* xr = x + (size_t)tk * H_;
  float acc[E_];
#pragma unroll
  for (int e = 0; e < E_; ++e) acc[e] = 0.f;
  int h0 = lane * 16;
#pragma unroll 4
  for (int i = 0; i < 16; ++i) {
    float xv = xr[h0 + i];
    const float* w = wr + (size_t)(h0 + i) * E_;
#pragma unroll
    for (int e = 0; e < E_; ++e) acc[e] = fmaf(xv, w[e], acc[e]);
  }
#pragma unroll
  for (int off = 32; off > 0; off >>= 1) {
#pragma unroll
    for (int e = 0; e < E_; ++e) acc[e] += __shfl_xor(acc[e], off, 64);
  }
  if (lane == 0) {
    int e0 = 0; float m0 = acc[0];
#pragma unroll
    for (int e = 1; e < E_; ++e) if (acc[e] > m0) { m0 = acc[e]; e0 = e; }
    int e1 = -1; float m1 = -1e30f;
#pragma unroll
    for (int e = 0; e < E_; ++e) if (e != e0 && acc[e] > m1) { m1 = acc[e]; e1 = e; }
    float s0 = 1.f / (1.f + __expf(m1 - m0));
    scores[tk * 2 + 0] = s0;
    scores[tk * 2 + 1] = 1.f - s0;
    int p0 = atomicAdd(&cnt[e0], 1); list[e0 * NTOK + p0] = tk * 2;
    int p1 = atomicAdd(&cnt[e1], 1); list[e1 * NTOK + p1] = tk * 2 + 1;
  }
}

// ---------------- 64k x 128n transpose-convert tile (proven R3) -------------
__device__ __forceinline__ void wtrans(const float* __restrict__ src,
                                       u16* __restrict__ dst, int K, int N,
                                       int k0, int n0, void* smem) {
  unsigned* lt = (unsigned*)smem;  // [128 n][32 u32 = 64 k]
  int t = threadIdx.x;
  int c = t & 31, kb = t >> 5;
  const float* sp = src + (size_t)(k0 + kb * 8) * N + n0 + (c << 2);
  float v[8][4];
#pragma unroll
  for (int j2 = 0; j2 < 8; ++j2) {
    float4 f = *(const float4*)(sp + (size_t)j2 * N);
    v[j2][0] = f.x; v[j2][1] = f.y; v[j2][2] = f.z; v[j2][3] = f.w;
  }
#pragma unroll
  for (int j = 0; j < 4; ++j) {
    int nl = (c << 2) + j;
    uint4 o = make_uint4(pk2(v[0][j], v[1][j]), pk2(v[2][j], v[3][j]),
                         pk2(v[4][j], v[5][j]), pk2(v[6][j], v[7][j]));
    *(uint4*)&lt[nl * 32 + ((kb ^ (c & 7)) << 2)] = o;
  }
  __syncthreads();
#pragma unroll
  for (int it = 0; it < 4; ++it) {
    int lin = it * 256 + t;
    int nl = lin >> 3, kq = lin & 7;
    uint4 o = *(const uint4*)&lt[nl * 32 + ((kq ^ ((nl >> 2) & 7)) << 2)];
    *(uint4*)(dst + (size_t)(n0 + nl) * K + k0 + kq * 8) = o;
  }
}

// ================= FAST PATH =================

// prep grid: [0,512) router | [512,1024) x->bf16 | [1024,3072) fc1T |
// [3072,3328) gwT | [3328,3584) uwT | [3584,4608) fc2T | [4608,4864) dwT
__global__ __launch_bounds__(256) void prep_k(
    const float* __restrict__ x, const float* __restrict__ wr,
    float* __restrict__ scores, int* __restrict__ cnt, int* __restrict__ list,
    u16* __restrict__ xb,
    const float* __restrict__ fc1, const float* __restrict__ fc2,
    const float* __restrict__ gw, const float* __restrict__ uw,
    const float* __restrict__ dw,
    u16* __restrict__ fc1T, u16* __restrict__ fc2T, u16* __restrict__ gwT,
    u16* __restrict__ uwT, u16* __restrict__ dwT) {
  __shared__ __align__(16) char psm[16384];
  int bid = blockIdx.x, t = threadIdx.x;
  if (bid < 512) {
    router_body(x, wr, scores, cnt, list, bid * 4 + (t >> 6));
    return;
  }
  if (bid < 1024) {
    const float4* srcx = (const float4*)x;
    ushort4* dstx = (ushort4*)xb;
    int base = (bid - 512) * 1024 + t;
#pragma unroll
    for (int it = 0; it < 4; ++it) {
      float4 v = srcx[base + it * 256];
      ushort4 o;
      o.x = f2bf(v.x); o.y = f2bf(v.y); o.z = f2bf(v.z); o.w = f2bf(v.w);
      dstx[base + it * 256] = o;
    }
    return;
  }
  if (bid < 3072) {        // fc1: 8 x [1024][2048], 16kt x 16nt each
    int b = bid - 1024;
    int e = b >> 8, q = b & 255;
    wtrans(fc1 + ((size_t)e << 21), fc1T + ((size_t)e << 21), 1024, 2048,
           (q & 15) * 64, (q >> 4) * 128, psm);
  } else if (bid < 3328) { // gw [1024][2048]
    int q = bid - 3072;
    wtrans(gw, gwT, 1024, 2048, (q & 15) * 64, (q >> 4) * 128, psm);
  } else if (bid < 3584) { // uw [1024][2048]
    int q = bid - 3328;
    wtrans(uw, uwT, 1024, 2048, (q & 15) * 64, (q >> 4) * 128, psm);
  } else if (bid < 4608) { // fc2: 8 x [1024][1024], 16kt x 8nt each
    int b = bid - 3584;
    int e = b >> 7, q = b & 127;
    wtrans(fc2 + ((size_t)e << 20), fc2T + ((size_t)e << 20), 1024, 1024,
           (q & 15) * 64, (q >> 4) * 128, psm);
  } else {                 // dw [2048][1024], 32kt x 8nt
    int q = bid - 4608;
    wtrans(dw, dwT, 2048, 1024, (q & 31) * 64, (q >> 5) * 128, psm);
  }
}

// L1: fused SwiGLU GEMMs, double-buffered LDS (2-phase prefetch).
// bid<256: G3 dense (gw/uw); else G1 expert (fc1). 128x128 tile, BK=32.
__global__ __launch_bounds__(256, 2) void swiglu_f_k(
    const u16* __restrict__ xb, const int* __restrict__ cnt,
    const int* __restrict__ list, const u16* __restrict__ fc1T,
    const u16* __restrict__ gwT, const u16* __restrict__ uwT,
    u16* __restrict__ act, u16* __restrict__ tmp) {
  __shared__ __align__(16) u16 As[2][128][32];
  __shared__ __align__(16) u16 B1s[2][128][32];
  __shared__ __align__(16) u16 B2s[2][128][32];

  int bid = blockIdx.x;
  int m0, n0, Me, obase = 0, ldo;
  const u16 *B1, *B2;
  const int* rowmap = nullptr;
  u16* Out;
  if (bid < 256) {  // G3: shared experts
    int mb = bid >> 4, nb = bid & 15;
    m0 = mb * 128; n0 = nb * 128; Me = NTOK;
    B1 = gwT + (size_t)n0 * 1024; B2 = uwT + (size_t)n0 * 1024;
    Out = tmp; ldo = ISH_;
  } else {  // G1: expert fc1
    int b2 = bid - 256; int e = b2 >> 7, r = b2 & 127, mb = r >> 3, nb = r & 7;
    Me = cnt[e]; m0 = mb * 128;
    if (m0 >= Me) return;
    n0 = nb * 128;
    rowmap = list + e * NTOK;
    const u16* fe = fc1T + ((size_t)e << 21);
    B1 = fe + (size_t)n0 * 1024;
    B2 = fe + (size_t)(1024 + n0) * 1024;
    int off = 0;
    for (int q = 0; q < e; ++q) off += cnt[q];
    obase = off;
    Out = act; ldo = I_;
  }
  int t = threadIdx.x, wid = t >> 6, lane = t & 63;
  int wm = wid & 1, wn = wid >> 1, lr = lane & 15, lkg = lane >> 4;
  int cq = lane & 3, crw = lane >> 2;

  const u16 *arow[2], *b1row[2], *b2row[2];
#pragma unroll
  for (int i = 0; i < 2; ++i) {
    int c = wid * 2 + i;
    int rl = m0 + c * 16 + crw;
    int rc = rl < Me ? rl : (Me - 1);
    int tok = rowmap ? (rowmap[rc] >> 1) : rc;
    arow[i] = xb + (size_t)tok * 1024 + cq * 8;
    int rb = c * 16 + crw;
    b1row[i] = B1 + (size_t)rb * 1024 + cq * 8;
    b2row[i] = B2 + (size_t)rb * 1024 + cq * 8;
  }

  auto stage = [&](int cb, int kk) {
#pragma unroll
    for (int i = 0; i < 2; ++i) {
      int c = wid * 2 + i;
      gl16(arow[i] + kk, (u16*)As + cb * 4096 + c * 512);
      gl16(b1row[i] + kk, (u16*)B1s + cb * 4096 + c * 512);
      gl16(b2row[i] + kk, (u16*)B2s + cb * 4096 + c * 512);
    }
  };

  f32x4 aP[4][4] = {}, aG[4][4] = {};
  auto compute = [&](int cb) {
    bf16x8 af[4];
#pragma unroll
    for (int f = 0; f < 4; ++f)
      af[f] = *(const bf16x8*)((u16*)As + cb * 4096 + (wm * 64 + f * 16 + lr) * 32 + lkg * 8);
#pragma unroll
    for (int fn = 0; fn < 4; ++fn) {
      bf16x8 b1 = *(const bf16x8*)((u16*)B1s + cb * 4096 + (wn * 64 + fn * 16 + lr) * 32 + lkg * 8);
      bf16x8 b2 = *(const bf16x8*)((u16*)B2s + cb * 4096 + (wn * 64 + fn * 16 + lr) * 32 + lkg * 8);
#pragma unroll
      for (int fm = 0; fm < 4; ++fm) {
        aP[fm][fn] = __builtin_amdgcn_mfma_f32_16x16x32_bf16(af[fm], b1, aP[fm][fn], 0, 0, 0);
        aG[fm][fn] = __builtin_amdgcn_mfma_f32_16x16x32_bf16(af[fm], b2, aG[fm][fn], 0, 0, 0);
      }
    }
  };

  stage(0, 0);
  __syncthreads();
  int cur = 0;
  for (int k0 = 32; k0 < 1024; k0 += 32) {
    stage(cur ^ 1, k0);   // prefetch next K-tile (in flight during compute)
    compute(cur);
    __syncthreads();      // drains vmcnt -> next tile ready; cur reads done
    cur ^= 1;
  }
  compute(cur);

#pragma unroll
  for (int fm = 0; fm < 4; ++fm)
#pragma unroll
    for (int fn = 0; fn < 4; ++fn)
#pragma unroll
      for (int j = 0; j < 4; ++j) {
        int row = m0 + wm * 64 + fm * 16 + lkg * 4 + j;
        if (row < Me) {
          float p = aP[fm][fn][j], g = aG[fm][fn][j];
          float s = p / (1.f + __expf(-p)) * g;
          Out[(size_t)(obase + row) * ldo + n0 + wn * 64 + fn * 16 + lr] = f2bf(s);
        }
      }
}

// L2': fused fc2-expert + down-proj GEMMs, dbuf, fp32 atomicAdd into out.
// MODE 0 (fc2): A=act local rows, B stride 1024, BN=128; v*score -> out[token].
// MODE 1 (down): A=tmp (+ks*1024), B stride 2048, BN=64, split-K2 -> out[row].
template <int MODE>
__device__ __forceinline__ void out_body(
    const u16* __restrict__ Ab, const u16* __restrict__ Bb, int Me, int m0,
    int n0, const int* __restrict__ listE, const float* __restrict__ scores,
    float* __restrict__ out, char* smem) {
  constexpr int BNx = MODE ? 64 : 128;
  constexpr int FN = BNx / 32;
  constexpr int KROW = MODE ? 2048 : 1024;  // row stride for both A and B
  constexpr int BCH = BNx / 64;             // B chunks per wave
  u16* As = (u16*)smem;            // [2][128][32]
  u16* Bs = (u16*)(smem + 16384);  // [2][BNx][32]

  int t = threadIdx.x, wid = t >> 6, lane = t & 63;
  int wm = wid & 1, wn = wid >> 1, lr = lane & 15, lkg = lane >> 4;
  int cq = lane & 3, crw = lane >> 2;

  const u16* arow[2];
#pragma unroll
  for (int i = 0; i < 2; ++i) {
    int c = wid * 2 + i;
    int rl = m0 + c * 16 + crw;
    int rc = rl < Me ? rl : (Me - 1);
    arow[i] = Ab + (size_t)rc * KROW + cq * 8;
  }
  const u16* brow[BCH];
#pragma unroll
  for (int i = 0; i < BCH; ++i) {
    int c = wid * BCH + i;
    brow[i] = Bb + (size_t)(c * 16 + crw) * KROW + cq * 8;
  }

  auto stage = [&](int cb, int kk) {
#pragma unroll
    for (int i = 0; i < 2; ++i)
      gl16(arow[i] + kk, As + cb * 4096 + (wid * 2 + i) * 512);
#pragma unroll
    for (int i = 0; i < BCH; ++i)
      gl16(brow[i] + kk, Bs + cb * (BNx * 32) + (wid * BCH + i) * 512);
  };

  f32x4 acc[4][FN] = {};
  auto compute = [&](int cb) {
    bf16x8 af[4];
#pragma unroll
    for (int f = 0; f < 4; ++f)
      af[f] = *(const bf16x8*)(As + cb * 4096 + (wm * 64 + f * 16 + lr) * 32 + lkg * 8);
#pragma unroll
    for (int fn = 0; fn < FN; ++fn) {
      bf16x8 bb = *(const bf16x8*)(Bs + cb * (BNx * 32) +
                                   (wn * (BNx / 2) + fn * 16 + lr) * 32 + lkg * 8);
#pragma unroll
      for (int fm = 0; fm < 4; ++fm)
        acc[fm][fn] = __builtin_amdgcn_mfma_f32_16x16x32_bf16(af[fm], bb, acc[fm][fn], 0, 0, 0);
    }
  };

  stage(0, 0);
  __syncthreads();
  int cur = 0;
  for (int k0 = 32; k0 < 1024; k0 += 32) {
    stage(cur ^ 1, k0);
    compute(cur);
    __syncthreads();
    cur ^= 1;
  }
  compute(cur);

#pragma unroll
  for (int fm = 0; fm < 4; ++fm)
#pragma unroll
    for (int fn = 0; fn < FN; ++fn)
#pragma unroll
      for (int j = 0; j < 4; ++j) {
        int row = m0 + wm * 64 + fm * 16 + lkg * 4 + j;
        if (row < Me) {
          float v = acc[fm][fn][j];
          int c = n0 + wn * (BNx / 2) + fn * 16 + lr;
          if (MODE == 0) {
            int slot = listE[row];
            atomicAdd(&out[(size_t)(slot >> 1) * H_ + c], v * scores[slot]);
          } else {
            atomicAdd(&out[(size_t)row * H_ + c], v);
          }
        }
      }
}

__global__ __launch_bounds__(256, 2) void out_f_k(
    const u16* __restrict__ act, const u16* __restrict__ fc2T,
    const u16* __restrict__ tmp, const u16* __restrict__ dwT,
    const int* __restrict__ cnt, const int* __restrict__ list,
    const float* __restrict__ scores, float* __restrict__ out) {
  __shared__ __align__(16) char smem[32768];
  int bid = blockIdx.x;
  if (bid < 1024) {  // fc2: e = bid>>7, 16 mtiles x 8 ntiles
    int e = bid >> 7, r = bid & 127, mb = r >> 3, nb = r & 7;
    int Me = cnt[e], m0 = mb * 128;
    if (m0 >= Me) return;
    int off = 0;
    for (int q = 0; q < e; ++q) off += cnt[q];
    out_body<0>(act + (size_t)off * 1024,
                fc2T + ((size_t)e << 20) + (size_t)(nb * 128) * 1024,
                Me, m0, nb * 128, list + e * NTOK, scores, out, smem);
  } else {  // down split-K2: ks in {0,1}, 16 mtiles x 16 ntiles
    int r = bid - 1024, ks = r >> 8, rr = r & 255, mb = rr >> 4, nb = rr & 15;
    out_body<1>(tmp + ks * 1024,
                dwT + (size_t)(nb * 64) * 2048 + ks * 1024,
                NTOK, mb * 128, nb * 64, nullptr, nullptr, out, smem);
  }
}

// ================= FALLBACK PATH (R1, proven) =================
#define BM 128
#define BN 64
#define BK 32
#define PK (BK + 8)

__global__ void router_k(const float* __restrict__ x, const float* __restrict__ wr,
                         float* __restrict__ scores, int* __restrict__ cnt,
                         int* __restrict__ list) {
  int wid = threadIdx.x >> 6;
  int tk = blockIdx.x * 4 + wid;
  if (tk >= NTOK) return;
  router_body(x, wr, scores, cnt, list, tk);
}

__global__ void offs_k(const int* __restrict__ cnt, int* __restrict__ offs) {
  if (threadIdx.x == 0 && blockIdx.x == 0) {
    int s = 0;
    for (int e = 0; e < E_; ++e) { offs[e] = s; s += cnt[e]; }
  }
}

__global__ void cvt_k(const float* __restrict__ x, u16* __restrict__ xb, int n4) {
  int i = blockIdx.x * blockDim.x + threadIdx.x;
  if (i >= n4) return;
  float4 v = reinterpret_cast<const float4*>(x)[i];
  ushort4 o;
  o.x = f2bf(v.x); o.y = f2bf(v.y); o.z = f2bf(v.z); o.w = f2bf(v.w);
  reinterpret_cast<ushort4*>(xb)[i] = o;
}

template <int EXPERT>
__global__ __launch_bounds__(256) void swiglu_gemm_k(
    const u16* __restrict__ A, int lda,
    const int* __restrict__ list, const int* __restrict__ cnt, const int* __restrict__ offs,
    const float* __restrict__ B1g, const float* __restrict__ B2g, int ldb, long long bstride,
    u16* __restrict__ Out, int ldo, int K) {
  __shared__ u16 As[BM][PK];
  __shared__ u16 Bs[2][BN][PK];
  int e = EXPERT ? blockIdx.z : 0;
  int Me = EXPERT ? cnt[e] : NTOK;
  int m0 = blockIdx.y * BM;
  if (m0 >= Me) return;
  int n0 = blockIdx.x * BN;
  const int* rowmap = EXPERT ? (list + e * NTOK) : nullptr;
  const float* B1 = B1g + (EXPERT ? (long long)e * bstride : 0);
  const float* B2 = B2g + (EXPERT ? (long long)e * bstride : 0);
  int t = threadIdx.x, wid = t >> 6, lane = t & 63;
  int wm = wid & 1, wn = wid >> 1, lr = lane & 15, lkg = lane >> 4;
  f32x4 accP[4][2] = {}, accG[4][2] = {};
  for (int k0 = 0; k0 < K; k0 += BK) {
#pragma unroll
    for (int it = 0; it < 2; ++it) {
      int idx = it * 256 + t, r = idx >> 2, q = idx & 3, row = m0 + r;
      uint4 v = make_uint4(0u, 0u, 0u, 0u);
      if (row < Me) {
        int rg = EXPERT ? (rowmap[row] >> 1) : row;
        v = *reinterpret_cast<const uint4*>(A + (size_t)rg * lda + k0 + q * 8);
      }
      *reinterpret_cast<uint4*>(&As[r][q * 8]) = v;
    }
#pragma unroll
    for (int b = 0; b < 2; ++b) {
      const float* Bp = b ? B2 : B1;
#pragma unroll
      for (int it = 0; it < 2; ++it) {
        int idx = (it * 256 + t) * 4, kr = idx >> 6, c = idx & 63;
        float4 f = *reinterpret_cast<const float4*>(Bp + (size_t)(k0 + kr) * ldb + n0 + c);
        Bs[b][c + 0][kr] = f2bf(f.x); Bs[b][c + 1][kr] = f2bf(f.y);
        Bs[b][c + 2][kr] = f2bf(f.z); Bs[b][c + 3][kr] = f2bf(f.w);
      }
    }
    __syncthreads();
    bf16x8 af[4];
#pragma unroll
    for (int fm = 0; fm < 4; ++fm)
      af[fm] = *reinterpret_cast<const bf16x8*>(&As[wm * 64 + fm * 16 + lr][lkg * 8]);
#pragma unroll
    for (int fn = 0; fn < 2; ++fn) {
      bf16x8 bp = *reinterpret_cast<const bf16x8*>(&Bs[0][wn * 32 + fn * 16 + lr][lkg * 8]);
      bf16x8 bg = *reinterpret_cast<const bf16x8*>(&Bs[1][wn * 32 + fn * 16 + lr][lkg * 8]);
#pragma unroll
      for (int fm = 0; fm < 4; ++fm) {
        accP[fm][fn] = __builtin_amdgcn_mfma_f32_16x16x32_bf16(af[fm], bp, accP[fm][fn], 0, 0, 0);
        accG[fm][fn] = __builtin_amdgcn_mfma_f32_16x16x32_bf16(af[fm], bg, accG[fm][fn], 0, 0, 0);
      }
    }
    __syncthreads();
  }
#pragma unroll
  for (int fm = 0; fm < 4; ++fm)
#pragma unroll
    for (int fn = 0; fn < 2; ++fn)
#pragma unroll
      for (int j = 0; j < 4; ++j) {
        int grow = wm * 64 + fm * 16 + lkg * 4 + j, gcol = wn * 32 + fn * 16 + lr;
        int row = m0 + grow;
        if (row < Me) {
          float p = accP[fm][fn][j], g = accG[fm][fn][j];
          float s = p / (1.f + __expf(-p)) * g;
          int orow = EXPERT ? (offs[e] + row) : row;
          Out[(size_t)orow * ldo + n0 + gcol] = f2bf(s);
        }
      }
}

template <int EXPERT>
__global__ __launch_bounds__(256) void out_gemm_k(
    const u16* __restrict__ A, int lda,
    const int* __restrict__ cnt, const int* __restrict__ offs,
    const int* __restrict__ list, const float* __restrict__ scores,
    const float* __restrict__ Bg, int ldb, long long bstride,
    float* __restrict__ Out, const float* __restrict__ outbuf, int K) {
  __shared__ u16 As[BM][PK];
  __shared__ u16 Bs[BN][PK];
  int e = EXPERT ? blockIdx.z : 0;
  int Me = EXPERT ? cnt[e] : NTOK;
  int m0 = blockIdx.y * BM;
  if (m0 >= Me) return;
  int n0 = blockIdx.x * BN;
  const float* B = Bg + (EXPERT ? (long long)e * bstride : 0);
  int aoff = EXPERT ? offs[e] : 0;
  int t = threadIdx.x, wid = t >> 6, lane = t & 63;
  int wm = wid & 1, wn = wid >> 1, lr = lane & 15, lkg = lane >> 4;
  f32x4 acc[4][2] = {};
  for (int k0 = 0; k0 < K; k0 += BK) {
#pragma unroll
    for (int it = 0; it < 2; ++it) {
      int idx = it * 256 + t, r = idx >> 2, q = idx & 3, row = m0 + r;
      uint4 v = make_uint4(0u, 0u, 0u, 0u);
      if (row < Me)
        v = *reinterpret_cast<const uint4*>(A + (size_t)(aoff + row) * lda + k0 + q * 8);
      *reinterpret_cast<uint4*>(&As[r][q * 8]) = v;
    }
#pragma unroll
    for (int it = 0; it < 2; ++it) {
      int idx = (it * 256 + t) * 4, kr = idx >> 6, c = idx & 63;
      float4 f = *reinterpret_cast<const float4*>(B + (size_t)(k0 + kr) * ldb + n0 + c);
      Bs[c + 0][kr] = f2bf(f.x); Bs[c + 1][kr] = f2bf(f.y);
      Bs[c + 2][kr] = f2bf(f.z); Bs[c + 3][kr] = f2bf(f.w);
    }
    __syncthreads();
    bf16x8 af[4];
#pragma unroll
    for (int fm = 0; fm < 4; ++fm)
      af[fm] = *reinterpret_cast<const bf16x8*>(&As[wm * 64 + fm * 16 + lr][lkg * 8]);
#pragma unroll
    for (int fn = 0; fn < 2; ++fn) {
      bf16x8 bb = *reinterpret_cast<const bf16x8*>(&Bs[wn * 32 + fn * 16 + lr][lkg * 8]);
#pragma unroll
      for (int fm = 0; fm < 4; ++fm)
        acc[fm][fn] = __builtin_amdgcn_mfma_f32_16x16x32_bf16(af[fm], bb, acc[fm][fn], 0, 0, 0);
    }
    __syncthreads();
  }
#pragma unroll
  for (int fm = 0; fm < 4; ++fm)
#pragma unroll
    for (int fn = 0; fn < 2; ++fn)
#pragma unroll
      for (int j = 0; j < 4; ++j) {
        int grow = wm * 64 + fm * 16 + lkg * 4 + j, gcol = wn * 32 + fn * 16 + lr;
        int row = m0 + grow;
        if (row < Me) {
          float v = acc[fm][fn][j];
          int c = n0 + gcol;
          if (EXPERT) {
            int slot = list[e * NTOK + row];
            Out[(size_t)slot * H_ + c] = v * scores[slot];
          } else {
            Out[(size_t)row * H_ + c] =
                v + outbuf[(size_t)(2 * row) * H_ + c] + outbuf[(size_t)(2 * row + 1) * H_ + c];
          }
        }
      }
}

// ---------------------------------------------------------------------------
extern "C" void kernel_launch(void* const* d_in, const int* in_sizes, int n_in,
                              void* d_out, int out_size, void* d_ws, size_t ws_size,
                              hipStream_t stream) {
  const float* x   = (const float*)d_in[0];
  const float* wr  = (const float*)d_in[1];
  const float* fc1 = (const float*)d_in[2];
  const float* fc2 = (const float*)d_in[3];
  const float* gw  = (const float*)d_in[4];
  const float* uw  = (const float*)d_in[5];
  const float* dw  = (const float*)d_in[6];
  float* out = (float*)d_out;
  char* ws = (char*)d_ws;

  const size_t NEED_FAST = 131072ull + (88ull << 20);
  if (ws_size >= NEED_FAST) {
    float* scores = (float*)ws;
    int* cnt  = (int*)(ws + 16384);
    int* list = (int*)(ws + 16512);
    u16* xb   = (u16*)(ws + 131072);
    u16* act  = (u16*)(ws + 131072 + (4ll << 20));
    u16* tmp  = (u16*)(ws + 131072 + (12ll << 20));
    u16* fc1T = (u16*)(ws + 131072 + (28ll << 20));
    u16* fc2T = (u16*)(ws + 131072 + (60ll << 20));
    u16* gwT  = (u16*)(ws + 131072 + (76ll << 20));
    u16* uwT  = (u16*)(ws + 131072 + (80ll << 20));
    u16* dwT  = (u16*)(ws + 131072 + (84ll << 20));

    hipMemsetAsync(cnt, 0, 128, stream);
    hipMemsetAsync(out, 0, (size_t)NTOK * H_ * sizeof(float), stream);
    prep_k<<<4864, 256, 0, stream>>>(x, wr, scores, cnt, list, xb,
                                     fc1, fc2, gw, uw, dw,
                                     fc1T, fc2T, gwT, uwT, dwT);
    swiglu_f_k<<<1280, 256, 0, stream>>>(xb, cnt, list, fc1T, gwT, uwT, act, tmp);
    out_f_k<<<1536, 256, 0, stream>>>(act, fc2T, tmp, dwT, cnt, list, scores, out);
  } else {
    float* scores = (float*)(ws);
    int*   cnt    = (int*)(ws + (16 << 10));
    int*   offs   = (int*)(ws + (16 << 10) + 128);
    int*   list   = (int*)(ws + (16 << 10) + 256);
    u16*   xb     = (u16*)(ws + (96 << 10));
    u16*   act    = (u16*)(ws + (96 << 10) + (4ll << 20));
    u16*   tmp    = (u16*)(ws + (96 << 10) + (12ll << 20));
    float* outbuf = (float*)(ws + (96 << 10) + (20ll << 20));

    hipMemsetAsync(cnt, 0, E_ * sizeof(int), stream);
    router_k<<<NTOK / 4, 256, 0, stream>>>(x, wr, scores, cnt, list);
    offs_k<<<1, 64, 0, stream>>>(cnt, offs);
    cvt_k<<<(NTOK * H_ / 4 + 255) / 256, 256, 0, stream>>>(x, xb, NTOK * H_ / 4);
    swiglu_gemm_k<1><<<dim3(I_ / BN, NTOK / BM, E_), 256, 0, stream>>>(
        xb, H_, list, cnt, offs, fc1, fc1 + I_, 2 * I_, (long long)H_ * 2 * I_, act, I_, H_);
    out_gemm_k<1><<<dim3(H_ / BN, NTOK / BM, E_), 256, 0, stream>>>(
        act, I_, cnt, offs, list, scores, fc2, H_, (long long)I_ * H_, outbuf, nullptr, I_);
    swiglu_gemm_k<0><<<dim3(ISH_ / BN, NTOK / BM, 1), 256, 0, stream>>>(
        xb, H_, nullptr, nullptr, nullptr, gw, uw, ISH_, 0, tmp, ISH_, H_);
    out_gemm_k<0><<<dim3(H_ / BN, NTOK / BM, 1), 256, 0, stream>>>(
        tmp, ISH_, nullptr, nullptr, nullptr, nullptr, dw, H_, 0, out, outbuf, ISH_);
  }
  (void)in_sizes; (void)n_in; (void)out_size;
}